// Round 6
// baseline (290.581 us; speedup 1.0000x reference)
//
#include <hip/hip_runtime.h>
#include <hip/hip_bf16.h>
#include <cstddef>
#include <cstdint>

#define B_    16
#define CIN_  256
#define COUT_ 128
#define H_    64
#define W_    64
#define OH_   128
#define OW_   128

// A-matrix row stride in shorts: 32 real k-values + 12 pad. 88-B rows give
// bank starts (22*nlo)%32 = all 16 even positions -> 2-way only (free).
// Verified round 1: SQ_LDS_BANK_CONFLICT 4.19M -> 0.
#define AST   44
#define ACHUNK (128*AST)          // shorts per (cls,chunk) A slice = 5632 (11264 B)

typedef __attribute__((ext_vector_type(8))) short bf16x8;
typedef __attribute__((ext_vector_type(4))) float f32x4;

__device__ inline short f2bf(float f) {
    __hip_bfloat16 h = __float2bfloat16(f);
    return *reinterpret_cast<short*>(&h);
}

__device__ inline void async_ld16(const void* g, void* l) {
    typedef const __attribute__((address_space(1))) unsigned int* gp_t;
    typedef __attribute__((address_space(3))) unsigned int* lp_t;
    __builtin_amdgcn_global_load_lds((gp_t)g, (lp_t)l, 16, 0, 0);
}

// ---------------------------------------------------------------------------
// Synth body: weights are b-invariant -> load once into REGISTERS, loop b.
// Block = (chunk, cog8): 8 ci x 8 co x 16 k slice. Thread (ci_l,co_l,kh) owns
// 4 kw elements of 5 tensors in regs; per b: compute, stage in 2KB LDS,
// copy-out via int2 (8B) stores (AST=44 rows are 88B: 8B-aligned only).
// Pad shorts [32,44) of each row are junk; consumer never reads them.
// ---------------------------------------------------------------------------
__device__ inline void synth_body(
    int chunk, int cog8, int tid,
    const float* __restrict__ weight,
    const float* __restrict__ tb, const float* __restrict__ tq,
    const float* __restrict__ tn, const float* __restrict__ tx,
    const float* __restrict__ mb, const float* __restrict__ mq,
    const float* __restrict__ mn, const float* __restrict__ mx,
    const float* __restrict__ feat,
    short* __restrict__ aws,
    short* lbuf /* [4 cls][8 co][32 k] shorts = 2KB, 16B aligned */)
{
    const int ci_l = tid >> 5;          // 0..7
    const int co_l = (tid >> 2) & 7;    // 0..7
    const int kh   = tid & 3;           // 0..3
    const int base = (chunk*8 + ci_l) * COUT_ + cog8*8 + co_l;

    const float4 w4 = *(const float4*)(weight + (size_t)base*16 + kh*4);
    const float4 b4 = *(const float4*)(tb + (size_t)base*16 + kh*4);
    const float4 q4 = *(const float4*)(tq + (size_t)base*16 + kh*4);
    const float4 n4 = *(const float4*)(tn + (size_t)base*16 + kh*4);
    const float4 x4 = *(const float4*)(tx + (size_t)base*16 + kh*4);
    const float m_b = mb[base], m_q = mq[base];
    const float m_n = mn[base], m_x = mx[base];
    const float* wp = (const float*)&w4;
    const float* bp = (const float*)&b4;
    const float* qp = (const float*)&q4;
    const float* np = (const float*)&n4;
    const float* xp = (const float*)&x4;

    const int r  = (kh+1)&1;
    const int dh = (kh<2) ? 1 : 0;

    // copy-out decode (per-thread constant)
    const int o_cls = tid >> 6;          // 0..3
    const int o_cor = (tid >> 3) & 7;    // 0..7
    const int o_e8  = tid & 7;           // 0..7 (int2 index within 32 shorts)

    for (int b = 0; b < 16; ++b) {
        const float sb = m_b * feat[b*4+0];
        const float sq = m_q * feat[b*4+1];
        const float sn = m_n * feat[b*4+2];
        const float sx = m_x * feat[b*4+3];
        #pragma unroll
        for (int kw = 0; kw < 4; ++kw) {
            int s  = (kw+1)&1;
            int dw = (kw<2) ? 1 : 0;
            float v = wp[kw] + sb*bp[kw] + sq*qp[kw] + sn*np[kw] + sx*xp[kw];
            lbuf[((r*2+s)*8 + co_l)*32 + (dh*2+dw)*8 + ci_l] = f2bf(v);
        }
        __syncthreads();
        {
            size_t row = ((((size_t)(b*4 + o_cls)*32 + chunk)*128)
                          + cog8*8 + o_cor);
            *(int2*)(aws + row*AST + o_e8*4) =
                *(const int2*)(lbuf + (o_cls*8 + o_cor)*32 + o_e8*4);
        }
        __syncthreads();
    }
}

// ---------------------------------------------------------------------------
// Transform body: x (fp32 NCHW) -> x_t bf16 [b][chunk32][ihp66][iwp66][ci8]
// with zero halo. float4 x-loads + padded [128][68] LDS transpose.
// ---------------------------------------------------------------------------
__device__ inline void transform_body(
    int ihp, int b, int tid,
    const float* __restrict__ x, short* __restrict__ xt,
    float* xls /* [128][68] floats */)
{
    const int4 z4 = {0, 0, 0, 0};

    if (ihp == 0 || ihp == 65) {       // border rows: zero all chunks/cols
        for (int j = tid; j < 2112; j += 256) {       // 32 chunks * 66 cols
            int c = j / 66, iwp = j - c*66;
            *(int4*)(xt + ((((size_t)b*32 + c)*66 + ihp)*66 + iwp)*8) = z4;
        }
        return;
    }
    if (tid < 64) {                    // border cols iwp in {0,65}
        int c = tid >> 1, iwp = (tid & 1) * 65;
        *(int4*)(xt + ((((size_t)b*32 + c)*66 + ihp)*66 + iwp)*8) = z4;
    }
    const int ih = ihp - 1;
    for (int half = 0; half < 2; ++half) {
        __syncthreads();
        #pragma unroll
        for (int it = 0; it < 8; ++it) {
            int ci_l = it*16 + (tid >> 4);
            int iw4  = (tid & 15) * 4;
            float4 v = *(const float4*)(
                x + (((size_t)b*256 + half*128 + ci_l)*64 + ih)*64 + iw4);
            *(float4*)(xls + ci_l*68 + iw4) = v;
        }
        __syncthreads();
        #pragma unroll
        for (int it2 = 0; it2 < 4; ++it2) {
            int chunk_l = it2*4 + (tid >> 6);
            int chunk   = half*16 + chunk_l;
            int iw      = tid & 63;
            short s8[8];
            #pragma unroll
            for (int j = 0; j < 8; ++j)
                s8[j] = f2bf(xls[(chunk_l*8 + j)*68 + iw]);
            *(int4*)(xt + ((((size_t)b*32 + chunk)*66 + ihp)*66 + (iw+1))*8)
                = *(const int4*)s8;
        }
    }
}

// ---------------------------------------------------------------------------
// Fused prep: transform blocks [0,1056) + synth blocks [1056,1568).
// ---------------------------------------------------------------------------
__global__ __launch_bounds__(256) void prep_fused(
    const float* __restrict__ x,
    const float* __restrict__ weight,
    const float* __restrict__ tb, const float* __restrict__ tq,
    const float* __restrict__ tn, const float* __restrict__ tx,
    const float* __restrict__ mb, const float* __restrict__ mq,
    const float* __restrict__ mn, const float* __restrict__ mx,
    const float* __restrict__ feat,
    short* __restrict__ aws, short* __restrict__ xt)
{
    __shared__ __align__(16) char smem[34816];   // max(2048 synth, 34816 xfrm)
    const int bid = blockIdx.x;
    const int tid = threadIdx.x;
    if (bid < 1056) {
        int ihp = bid % 66, b = bid / 66;
        transform_body(ihp, b, tid, x, xt, (float*)smem);
    } else {
        int sb = bid - 1056;             // 0..511
        int chunk = sb & 31, cog8 = sb >> 5;
        synth_body(chunk, cog8, tid, weight, tb, tq, tn, tx,
                   mb, mq, mn, mx, feat, aws, (short*)smem);
    }
}

// Standalone synth (gather-fallback path only). grid (32, 16).
__global__ __launch_bounds__(256) void synth_aws(
    const float* __restrict__ weight,
    const float* __restrict__ tb, const float* __restrict__ tq,
    const float* __restrict__ tn, const float* __restrict__ tx,
    const float* __restrict__ mb, const float* __restrict__ mq,
    const float* __restrict__ mn, const float* __restrict__ mx,
    const float* __restrict__ feat,
    short* __restrict__ aws)
{
    __shared__ __align__(16) short lbuf[4][8][32];
    synth_body(blockIdx.x, blockIdx.y, threadIdx.x, weight, tb, tq, tn, tx,
               mb, mq, mn, mx, feat, aws, &lbuf[0][0][0]);
}

// ---------------------------------------------------------------------------
// Kernel C v5: wide tile 128co x 256px + SPLIT-BARRIER COUNTED-VMCNT pipeline
// (T4). Round-5 diagnosis: no pipe saturated (MFMA 307cy, LDS ~1000cy,
// measured 1670cy per 2-block step) -> the __syncthreads vmcnt(0) drain
// serialized DMA latency every chunk. New schedule per chunk:
//   barrier#1 (readers of buf[sel^1] done) -> issue stage(c+1) ->
//   s_waitcnt vmcnt(4) (own stage(c) done; c+1 in flight) ->
//   barrier#2 (buf[sel] collectively full) -> ds_read + MFMA.
// Every thread issues exactly 4 DMAs/stage -> uniform counted vmcnt is valid
// across the barrier (HK/m218 pattern). DMA latency now hides under MFMA.
// ---------------------------------------------------------------------------
__global__ __launch_bounds__(256, 2) void deconv_mfma5(
    const short* __restrict__ aws, const short* __restrict__ xt,
    const float* __restrict__ bias, const float* __restrict__ prelu_a,
    float* __restrict__ out)
{
    const int tid  = threadIdx.x;
    const int lane = tid & 63;
    const int wv   = tid >> 6;
    const int wm   = wv & 1, wn = wv >> 1;
    const int o    = blockIdx.x;              // 0..1023
    const int x8   = o & 7;
    const int l    = o >> 3;                  // 0..127
    const int cls  = l & 3;
    const int nt2  = (l >> 2) & 15;
    const int b    = 2*x8 + (l >> 6);
    const int a0 = (nt2 >> 1) * 8, c0 = (nt2 & 1) * 32;
    const int r = cls >> 1, s = cls & 1;

    __shared__ __align__(16) short als[2][ACHUNK];  // A: [co128][AST44] 2x11264B
    __shared__ __align__(16) short xsb[2][2560];    // B: [row9][col33][ci8] 2x5120B

    // ---- staging plan: t = wv + i*4 (16 transfers exactly, 4 per thread) ----
    // t<11: A slice (11 x 1KB); t=11..15: B tile 9x33 px (297x16B, clamped)
    const short* gb[4]; size_t gstep[4]; int loff[4], isB[4];
    {
        const size_t awb = (((size_t)b*4 + cls)*32) * ACHUNK;
        #pragma unroll
        for (int i = 0; i < 4; ++i) {
            int t = wv + i*4;
            if (t < 11) {
                gb[i]    = aws + awb + t*512 + lane*8;
                gstep[i] = ACHUNK;  loff[i] = t*512;  isB[i] = 0;
            } else {
                int j = t - 11;                     // 0..4
                int p = j*64 + lane; if (p > 296) p = 296;
                int row = p / 33, col = p - row*33;
                gb[i] = xt + (((size_t)b*32*66 + (a0 + r + row))*66
                              + (c0 + s + col)) * 8;
                gstep[i] = 66*66*8;  loff[i] = j*512;  isB[i] = 1;
            }
        }
    }

    f32x4 acc[4][8];
    #pragma unroll
    for (int mi = 0; mi < 4; ++mi)
        #pragma unroll
        for (int ni = 0; ni < 8; ++ni)
            acc[mi][ni] = (f32x4){0.f, 0.f, 0.f, 0.f};

    const int nlo = lane & 15;
    const int q   = lane >> 4;
    const int dh  = q >> 1, dw = q & 1;

    // prologue: stage chunk 0 into buffer 0 (4 outstanding/thread)
    #pragma unroll
    for (int i = 0; i < 4; ++i)
        async_ld16(gb[i], isB[i] ? &xsb[0][loff[i]] : &als[0][loff[i]]);

    for (int c = 0; c < 32; ++c) {
        const int sel = c & 1;
        // barrier #1: all waves finished reading buf[sel^1] in iter c-1
        // (their ds_reads completed before their MFMAs consumed them), so
        // it is WAR-safe to DMA chunk c+1 into it.
        __builtin_amdgcn_s_barrier();
        if (c < 31) {
            const int ps = sel ^ 1;
            #pragma unroll
            for (int i = 0; i < 4; ++i)
                async_ld16(gb[i] + (size_t)(c+1)*gstep[i],
                           isB[i] ? &xsb[ps][loff[i]] : &als[ps][loff[i]]);
            // own chunk-c loads (4 oldest) done; chunk-c+1 stays in flight
            asm volatile("s_waitcnt vmcnt(4)" ::: "memory");
        } else {
            asm volatile("s_waitcnt vmcnt(0)" ::: "memory");
        }
        // barrier #2: every wave passed its counted wait -> buf[sel] full.
        __builtin_amdgcn_s_barrier();
        asm volatile("" ::: "memory");   // keep ds_reads below barrier #2

        bf16x8 af[4], bfr[8];
        #pragma unroll
        for (int mi = 0; mi < 4; ++mi)
            af[mi] = *(const bf16x8*)(&als[sel][(wm*64 + mi*16 + nlo)*AST + q*8]);
        #pragma unroll
        for (int ni = 0; ni < 8; ++ni) {
            int a_local = wn*4 + (ni & 3);
            int colx    = nlo + (ni >> 2)*16 + dw;
            bfr[ni] = *(const bf16x8*)(&xsb[sel][((a_local + dh)*33 + colx)*8]);
        }
        #pragma unroll
        for (int mi = 0; mi < 4; ++mi)
            #pragma unroll
            for (int ni = 0; ni < 8; ++ni)
                acc[mi][ni] = __builtin_amdgcn_mfma_f32_16x16x32_bf16(
                    af[mi], bfr[ni], acc[mi][ni], 0, 0, 0);
    }

    // ---- epilogue: bias + PReLU ----
    const float pa = prelu_a[0];
    #pragma unroll
    for (int mi = 0; mi < 4; ++mi) {
        #pragma unroll
        for (int reg = 0; reg < 4; ++reg) {
            int co = wm*64 + mi*16 + q*4 + reg;
            float bv = bias[co];
            #pragma unroll
            for (int ni = 0; ni < 8; ++ni) {
                int a_local = wn*4 + (ni & 3);
                int cg      = ni >> 2;
                int oh = 2*(a0 + a_local) + r;
                int ow = 2*(c0 + cg*16 + nlo) + s;
                float v = acc[mi][ni][reg] + bv;
                v = (v >= 0.f) ? v : pa*v;
                out[(((size_t)b*COUT_ + co)*OH_ + oh)*OW_ + ow] = v;
            }
        }
    }
}

// ---------------------------------------------------------------------------
// Middle fallback: gather-based MFMA deconv (needs only aws in ws).
// A loads via 2x int2 (AST=44 rows are 8B-aligned only).
// ---------------------------------------------------------------------------
__global__ __launch_bounds__(256, 2) void deconv_mfma_gather(
    const float* __restrict__ x,
    const short* __restrict__ aws,
    const float* __restrict__ bias,
    const float* __restrict__ prelu_a,
    float* __restrict__ out)
{
    const int tid  = threadIdx.x;
    const int lane = tid & 63;
    const int wv   = tid >> 6;
    const int wm   = wv & 1, wn = wv >> 1;
    const int nt   = blockIdx.x;
    const int cls  = blockIdx.y;
    const int b    = blockIdx.z;
    const int a0 = (nt >> 2) * 8, c0 = (nt & 3) * 16;
    const int r = cls >> 1, s = cls & 1;

    __shared__ __align__(16) short xs[1280];

    int goff[5], gstep[5], gok[5];
    #pragma unroll
    for (int i = 0; i < 5; ++i) {
        int e    = tid + i*256;
        int ci_l = e & 7;
        int rc   = e >> 3;
        int row  = rc / 17;
        int col  = rc - row*17;
        int ih   = a0 - 1 + r + row;
        int iw   = c0 - 1 + s + col;
        int ok   = (rc < 153) && ((unsigned)ih < (unsigned)H_)
                              && ((unsigned)iw < (unsigned)W_);
        goff[i]  = ok ? (((b*CIN_ + ci_l)*H_ + ih)*W_ + iw) : 0;
        gstep[i] = ok ? (8*H_*W_) : 0;
        gok[i]   = ok;
    }
    const int nlo = lane & 15;
    const int q   = lane >> 4;
    const int dh  = q >> 1, dw = q & 1;

    const size_t awb = (((size_t)b*4 + cls)*32) * ACHUNK;
    const short* agp = aws + awb + (wm*64 + nlo)*AST + q*8;

    f32x4 acc[4][4];
    #pragma unroll
    for (int mi = 0; mi < 4; ++mi)
        #pragma unroll
        for (int ni = 0; ni < 4; ++ni)
            acc[mi][ni] = (f32x4){0.f, 0.f, 0.f, 0.f};

    for (int chunk = 0; chunk < 32; ++chunk) {
        __syncthreads();
        #pragma unroll
        for (int i = 0; i < 5; ++i) {
            float v = x[goff[i] + chunk*gstep[i]];
            v = gok[i] ? v : 0.0f;
            xs[tid + i*256] = f2bf(v);
        }
        bf16x8 af[4];
        #pragma unroll
        for (int mi = 0; mi < 4; ++mi) {
            const short* p = agp + (size_t)chunk*ACHUNK + mi*16*AST;
            union { int2 h[2]; bf16x8 v; } u;
            u.h[0] = *(const int2*)p;
            u.h[1] = *(const int2*)(p + 4);
            af[mi] = u.v;
        }
        __syncthreads();
        bf16x8 bfr[4];
        #pragma unroll
        for (int ni = 0; ni < 4; ++ni) {
            int a_local = wn*4 + ni;
            bfr[ni] = *(const bf16x8*)(xs + ((a_local + dh)*17 + (nlo + dw))*8);
        }
        #pragma unroll
        for (int mi = 0; mi < 4; ++mi)
            #pragma unroll
            for (int ni = 0; ni < 4; ++ni)
                acc[mi][ni] = __builtin_amdgcn_mfma_f32_16x16x32_bf16(
                    af[mi], bfr[ni], acc[mi][ni], 0, 0, 0);
    }

    const float pa = prelu_a[0];
    #pragma unroll
    for (int mi = 0; mi < 4; ++mi) {
        #pragma unroll
        for (int reg = 0; reg < 4; ++reg) {
            int co = wm*64 + mi*16 + q*4 + reg;
            float bv = bias[co];
            #pragma unroll
            for (int ni = 0; ni < 4; ++ni) {
                int a_local = wn*4 + ni;
                int oh = 2*(a0 + a_local) + r;
                int ow = 2*(c0 + nlo) + s;
                float v = acc[mi][ni][reg] + bv;
                v = (v >= 0.f) ? v : pa*v;
                out[(((size_t)b*COUT_ + co)*OH_ + oh)*OW_ + ow] = v;
            }
        }
    }
}

// ---------------------------------------------------------------------------
// Last-resort fallback: fp32 direct kernel, in-kernel weight synthesis, no ws.
// ---------------------------------------------------------------------------
__global__ __launch_bounds__(256) void deconv_fallback(
    const float* __restrict__ x,
    const float* __restrict__ weight,
    const float* __restrict__ tb, const float* __restrict__ tq,
    const float* __restrict__ tn, const float* __restrict__ tx,
    const float* __restrict__ mb, const float* __restrict__ mq,
    const float* __restrict__ mn, const float* __restrict__ mx,
    const float* __restrict__ feat,
    const float* __restrict__ bias, const float* __restrict__ prelu_a,
    float* __restrict__ out)
{
    const int tid    = threadIdx.x;
    const int tile   = blockIdx.x;
    const int coT    = blockIdx.y;
    const int b      = blockIdx.z;
    const int tile_h = tile >> 3, tile_w = tile & 7;
    const int a0 = tile_h * 8;
    const int c0 = tile_w * 8;
    const int co0 = coT * 64;

    const int tco = tid & 15;
    const int tpx = tid >> 4;
    const int rr  = tpx >> 2, rc = tpx & 3;

    __shared__ float xsf[4][100];
    __shared__ float wsh[4][16][64];

    float acc[4][4][4];
    #pragma unroll
    for (int i = 0; i < 4; ++i)
        #pragma unroll
        for (int j = 0; j < 4; ++j)
            #pragma unroll
            for (int c = 0; c < 4; ++c) acc[i][j][c] = 0.f;

    float f0 = feat[b*4 + 0], f1 = feat[b*4 + 1];
    float f2 = feat[b*4 + 2], f3 = feat[b*4 + 3];

    for (int chunk = 0; chunk < CIN_ / 4; ++chunk) {
        const int ci0 = chunk * 4;
        __syncthreads();
        for (int e = tid; e < 400; e += 256) {
            int ci_l = e / 100; int rem = e - ci_l * 100;
            int rI = rem / 10;  int cI = rem - rI * 10;
            int ih = a0 - 1 + rI, iw = c0 - 1 + cI;
            float v = 0.f;
            if ((unsigned)ih < (unsigned)H_ && (unsigned)iw < (unsigned)W_)
                v = x[(((size_t)b * CIN_ + ci0 + ci_l) * H_ + ih) * W_ + iw];
            xsf[ci_l][rem] = v;
        }
        #pragma unroll
        for (int k = 0; k < 4; ++k) {
            int g = tid + k * 256;
            int ci_l = g >> 8; int rrem = g & 255;
            int co_l = rrem >> 2; int tg = (rrem & 3) * 4;
            int cico = (ci0 + ci_l) * COUT_ + co0 + co_l;
            int e = cico * 16 + tg;
            float4 w  = *(const float4*)(weight + e);
            float4 vb = *(const float4*)(tb + e);
            float4 vq = *(const float4*)(tq + e);
            float4 vn = *(const float4*)(tn + e);
            float4 vx = *(const float4*)(tx + e);
            float sb = mb[cico] * f0, sq = mq[cico] * f1;
            float sn = mn[cico] * f2, sx = mx[cico] * f3;
            float4 wvv;
            wvv.x = w.x + sb*vb.x + sq*vq.x + sn*vn.x + sx*vx.x;
            wvv.y = w.y + sb*vb.y + sq*vq.y + sn*vn.y + sx*vx.y;
            wvv.z = w.z + sb*vb.z + sq*vq.z + sn*vn.z + sx*vx.z;
            wvv.w = w.w + sb*vb.w + sq*vq.w + sn*vn.w + sx*vx.w;
            wsh[ci_l][tg + 0][co_l] = wvv.x;
            wsh[ci_l][tg + 1][co_l] = wvv.y;
            wsh[ci_l][tg + 2][co_l] = wvv.z;
            wsh[ci_l][tg + 3][co_l] = wvv.w;
        }
        __syncthreads();
        #pragma unroll
        for (int ci_l = 0; ci_l < 4; ++ci_l) {
            float xpv[4][4];
            #pragma unroll
            for (int i = 0; i < 4; ++i)
                #pragma unroll
                for (int j = 0; j < 4; ++j)
                    xpv[i][j] = xsf[ci_l][(rr*2 + i) * 10 + rc*2 + j];
            #pragma unroll
            for (int kh = 0; kh < 4; ++kh) {
                const int rpar = (kh & 1) ? 0 : 1;
                const int offh = (kh == 0) ? 2 : (kh == 3) ? 0 : 1;
                #pragma unroll
                for (int kw = 0; kw < 4; ++kw) {
                    const int spar = (kw & 1) ? 0 : 1;
                    const int offw = (kw == 0) ? 2 : (kw == 3) ? 0 : 1;
                    float4 wvv = *(const float4*)&wsh[ci_l][kh*4 + kw][tco*4];
                    float wr[4] = {wvv.x, wvv.y, wvv.z, wvv.w};
                    #pragma unroll
                    for (int da = 0; da < 2; ++da)
                        #pragma unroll
                        for (int dc = 0; dc < 2; ++dc) {
                            const float xvv = xpv[da + offh][dc + offw];
                            #pragma unroll
                            for (int cc = 0; cc < 4; ++cc)
                                acc[2*da + rpar][2*dc + spar][cc] =
                                    fmaf(wr[cc], xvv, acc[2*da + rpar][2*dc + spar][cc]);
                        }
                }
            }
        }
    }
    const float pa  = prelu_a[0];
    const int oh0 = tile_h * 16 + rr * 4;
    const int ow0 = tile_w * 16 + rc * 4;
    #pragma unroll
    for (int cc = 0; cc < 4; ++cc) {
        const int co = co0 + tco * 4 + cc;
        const float bv = bias[co];
        #pragma unroll
        for (int dr = 0; dr < 4; ++dr)
            #pragma unroll
            for (int dw2 = 0; dw2 < 4; ++dw2) {
                float v = acc[dr][dw2][cc] + bv;
                v = (v >= 0.f) ? v : pa * v;
                out[(((size_t)b * COUT_ + co) * OH_ + (oh0 + dr)) * OW_ + (ow0 + dw2)] = v;
            }
    }
}

extern "C" void kernel_launch(void* const* d_in, const int* in_sizes, int n_in,
                              void* d_out, int out_size, void* d_ws, size_t ws_size,
                              hipStream_t stream) {
    (void)in_sizes; (void)n_in; (void)out_size;
    const float* x      = (const float*)d_in[0];
    const float* feat   = (const float*)d_in[1];
    const float* weight = (const float*)d_in[2];
    const float* tb     = (const float*)d_in[3];
    const float* tq     = (const float*)d_in[4];
    const float* tn     = (const float*)d_in[5];
    const float* tx     = (const float*)d_in[6];
    const float* mb     = (const float*)d_in[7];
    const float* mq     = (const float*)d_in[8];
    const float* mn     = (const float*)d_in[9];
    const float* mx     = (const float*)d_in[10];
    const float* bias   = (const float*)d_in[11];
    const float* prelu  = (const float*)d_in[12];
    float* out = (float*)d_out;

    const size_t aws_sz = (size_t)B_ * 4 * 32 * 128 * AST * sizeof(short);  // 23.07 MB
    const size_t xt_sz  = (size_t)B_ * 32 * 66 * 66 * 8 * sizeof(short);    // 35.68 MB

    if (ws_size >= aws_sz + xt_sz) {
        short* aws = (short*)d_ws;
        short* xt  = (short*)((char*)d_ws + aws_sz);
        prep_fused<<<dim3(1056 + 512), 256, 0, stream>>>(
            x, weight, tb, tq, tn, tx, mb, mq, mn, mx, feat, aws, xt);
        deconv_mfma5<<<dim3(1024), 256, 0, stream>>>(
            aws, xt, bias, prelu, out);
    } else if (ws_size >= aws_sz) {
        short* aws = (short*)d_ws;
        synth_aws<<<dim3(32, 16), 256, 0, stream>>>(
            weight, tb, tq, tn, tx, mb, mq, mn, mx, feat, aws);
        deconv_mfma_gather<<<dim3(32, 4, 16), 256, 0, stream>>>(
            x, aws, bias, prelu, out);
    } else {
        deconv_fallback<<<dim3(64, 2, 16), 256, 0, stream>>>(
            x, weight, tb, tq, tn, tx, mb, mq, mn, mx, feat, bias, prelu, out);
    }
}

// Round 7
// 279.300 us; speedup vs baseline: 1.0404x; 1.0404x over previous
//
#include <hip/hip_runtime.h>
#include <hip/hip_bf16.h>
#include <cstddef>
#include <cstdint>

#define B_    16
#define CIN_  256
#define COUT_ 128
#define H_    64
#define W_    64
#define OH_   128
#define OW_   128

// Dense A rows: 32 shorts (64 B, fully aligned full-line stores in synth).
// Bank spread for the MFMA A-read comes from a baked XOR swizzle instead of
// padding: byte_off' = byte_off ^ ((row&7)<<4), applied identically at
// synth-write and deconv-read (the permutation lives in the data, so the
// linear global_load_lds copy is oblivious to it). Lane bank math: 16 lanes
// land on 8 distinct 16B slots covering all 32 banks -> 2-way = free.
#define ACH   4096                // shorts per (cls,chunk) A slice (8192 B)

typedef __attribute__((ext_vector_type(8))) short bf16x8;
typedef __attribute__((ext_vector_type(4))) float f32x4;

__device__ inline short f2bf(float f) {
    __hip_bfloat16 h = __float2bfloat16(f);
    return *reinterpret_cast<short*>(&h);
}

__device__ inline void async_ld16(const void* g, void* l) {
    typedef const __attribute__((address_space(1))) unsigned int* gp_t;
    typedef __attribute__((address_space(3))) unsigned int* lp_t;
    __builtin_amdgcn_global_load_lds((gp_t)g, (lp_t)l, 16, 0, 0);
}

// ---------------------------------------------------------------------------
// Synth body: weights are b-invariant -> load once into REGISTERS, loop b.
// Block = (chunk, cog8): 8 ci x 8 co x 16 k slice. Per b: compute, stage in
// 2KB LDS, copy-out int2 to the dense SWIZZLED aws layout (full 64B lines:
// the XOR permutes within 512B windows that the block covers completely).
// ---------------------------------------------------------------------------
__device__ inline void synth_body(
    int chunk, int cog8, int tid,
    const float* __restrict__ weight,
    const float* __restrict__ tb, const float* __restrict__ tq,
    const float* __restrict__ tn, const float* __restrict__ tx,
    const float* __restrict__ mb, const float* __restrict__ mq,
    const float* __restrict__ mn, const float* __restrict__ mx,
    const float* __restrict__ feat,
    short* __restrict__ aws,
    short* lbuf /* [4 cls][8 co][32 k] shorts = 2KB, 16B aligned */)
{
    const int ci_l = tid >> 5;          // 0..7
    const int co_l = (tid >> 2) & 7;    // 0..7
    const int kh   = tid & 3;           // 0..3
    const int base = (chunk*8 + ci_l) * COUT_ + cog8*8 + co_l;

    const float4 w4 = *(const float4*)(weight + (size_t)base*16 + kh*4);
    const float4 b4 = *(const float4*)(tb + (size_t)base*16 + kh*4);
    const float4 q4 = *(const float4*)(tq + (size_t)base*16 + kh*4);
    const float4 n4 = *(const float4*)(tn + (size_t)base*16 + kh*4);
    const float4 x4 = *(const float4*)(tx + (size_t)base*16 + kh*4);
    const float m_b = mb[base], m_q = mq[base];
    const float m_n = mn[base], m_x = mx[base];
    const float* wp = (const float*)&w4;
    const float* bp = (const float*)&b4;
    const float* qp = (const float*)&q4;
    const float* np = (const float*)&n4;
    const float* xp = (const float*)&x4;

    const int r  = (kh+1)&1;
    const int dh = (kh<2) ? 1 : 0;

    // copy-out decode (per-thread constant)
    const int o_cls = tid >> 6;          // 0..3
    const int o_cor = (tid >> 3) & 7;    // 0..7 (row within cog8 group; =row&7)
    const int o_e8  = tid & 7;           // 0..7 (8B block within 64B row)
    const int o_off = (((cog8*8 + o_cor)*64 + o_e8*8) ^ (o_cor << 4)); // bytes

    for (int b = 0; b < 16; ++b) {
        const float sb = m_b * feat[b*4+0];
        const float sq = m_q * feat[b*4+1];
        const float sn = m_n * feat[b*4+2];
        const float sx = m_x * feat[b*4+3];
        #pragma unroll
        for (int kw = 0; kw < 4; ++kw) {
            int s  = (kw+1)&1;
            int dw = (kw<2) ? 1 : 0;
            float v = wp[kw] + sb*bp[kw] + sq*qp[kw] + sn*np[kw] + sx*xp[kw];
            lbuf[((r*2+s)*8 + co_l)*32 + (dh*2+dw)*8 + ci_l] = f2bf(v);
        }
        __syncthreads();
        {
            size_t sbase = ((size_t)(b*4 + o_cls)*32 + chunk) * ACH;  // shorts
            *(int2*)(aws + sbase + (o_off >> 1)) =
                *(const int2*)(lbuf + (o_cls*8 + o_cor)*32 + o_e8*4);
        }
        __syncthreads();
    }
}

// ---------------------------------------------------------------------------
// Transform body: x (fp32 NCHW) -> x_t bf16 [b][chunk32][ihp66][iwp66][ci8]
// with zero halo. float4 x-loads + padded [128][68] LDS transpose.
// ---------------------------------------------------------------------------
__device__ inline void transform_body(
    int ihp, int b, int tid,
    const float* __restrict__ x, short* __restrict__ xt,
    float* xls /* [128][68] floats */)
{
    const int4 z4 = {0, 0, 0, 0};

    if (ihp == 0 || ihp == 65) {       // border rows: zero all chunks/cols
        for (int j = tid; j < 2112; j += 256) {       // 32 chunks * 66 cols
            int c = j / 66, iwp = j - c*66;
            *(int4*)(xt + ((((size_t)b*32 + c)*66 + ihp)*66 + iwp)*8) = z4;
        }
        return;
    }
    if (tid < 64) {                    // border cols iwp in {0,65}
        int c = tid >> 1, iwp = (tid & 1) * 65;
        *(int4*)(xt + ((((size_t)b*32 + c)*66 + ihp)*66 + iwp)*8) = z4;
    }
    const int ih = ihp - 1;
    for (int half = 0; half < 2; ++half) {
        __syncthreads();
        #pragma unroll
        for (int it = 0; it < 8; ++it) {
            int ci_l = it*16 + (tid >> 4);
            int iw4  = (tid & 15) * 4;
            float4 v = *(const float4*)(
                x + (((size_t)b*256 + half*128 + ci_l)*64 + ih)*64 + iw4);
            *(float4*)(xls + ci_l*68 + iw4) = v;
        }
        __syncthreads();
        #pragma unroll
        for (int it2 = 0; it2 < 4; ++it2) {
            int chunk_l = it2*4 + (tid >> 6);
            int chunk   = half*16 + chunk_l;
            int iw      = tid & 63;
            short s8[8];
            #pragma unroll
            for (int j = 0; j < 8; ++j)
                s8[j] = f2bf(xls[(chunk_l*8 + j)*68 + iw]);
            *(int4*)(xt + ((((size_t)b*32 + chunk)*66 + ihp)*66 + (iw+1))*8)
                = *(const int4*)s8;
        }
    }
}

// ---------------------------------------------------------------------------
// Fused prep: transform blocks [0,1056) + synth blocks [1056,1568).
// ---------------------------------------------------------------------------
__global__ __launch_bounds__(256) void prep_fused(
    const float* __restrict__ x,
    const float* __restrict__ weight,
    const float* __restrict__ tb, const float* __restrict__ tq,
    const float* __restrict__ tn, const float* __restrict__ tx,
    const float* __restrict__ mb, const float* __restrict__ mq,
    const float* __restrict__ mn, const float* __restrict__ mx,
    const float* __restrict__ feat,
    short* __restrict__ aws, short* __restrict__ xt)
{
    __shared__ __align__(16) char smem[34816];   // max(2048 synth, 34816 xfrm)
    const int bid = blockIdx.x;
    const int tid = threadIdx.x;
    if (bid < 1056) {
        int ihp = bid % 66, b = bid / 66;
        transform_body(ihp, b, tid, x, xt, (float*)smem);
    } else {
        int sb = bid - 1056;             // 0..511
        int chunk = sb & 31, cog8 = sb >> 5;
        synth_body(chunk, cog8, tid, weight, tb, tq, tn, tx,
                   mb, mq, mn, mx, feat, aws, (short*)smem);
    }
}

// Standalone synth (gather-fallback path only). grid (32, 16).
__global__ __launch_bounds__(256) void synth_aws(
    const float* __restrict__ weight,
    const float* __restrict__ tb, const float* __restrict__ tq,
    const float* __restrict__ tn, const float* __restrict__ tx,
    const float* __restrict__ mb, const float* __restrict__ mq,
    const float* __restrict__ mn, const float* __restrict__ mx,
    const float* __restrict__ feat,
    short* __restrict__ aws)
{
    __shared__ __align__(16) short lbuf[4][8][32];
    synth_body(blockIdx.x, blockIdx.y, threadIdx.x, weight, tb, tq, tn, tx,
               mb, mq, mn, mx, feat, aws, &lbuf[0][0][0]);
}

// ---------------------------------------------------------------------------
// Kernel C v6: wide tile 128co x 256px, BK=64 (two ci-chunks per barrier).
// Round-6 diagnosis: per-iteration fixed cost (barrier skew + DMA drain) is
// ~2300cy vs LDS floor 1000cy and MFMA floor 307cy per paired step; neither
// throughput-bound. Halving iteration count (32 -> 16) amortizes the fixed
// cost over 2x compute. Keep the PROVEN __syncthreads-then-issue structure
// (mfma5's raw-barrier counted-vmcnt regressed: compiler adds its own
// vmcnt(0) before aliasing ds_reads). Dense swizzled aws: A DMA 8 transfers
// per chunk (was 11), B 5 -> 26 per double-chunk, <=7 per thread.
// ---------------------------------------------------------------------------
__global__ __launch_bounds__(256, 2) void deconv_mfma6(
    const short* __restrict__ aws, const short* __restrict__ xt,
    const float* __restrict__ bias, const float* __restrict__ prelu_a,
    float* __restrict__ out)
{
    const int tid  = threadIdx.x;
    const int lane = tid & 63;
    const int wv   = tid >> 6;
    const int wm   = wv & 1, wn = wv >> 1;
    const int o    = blockIdx.x;              // 0..1023
    const int x8   = o & 7;
    const int l    = o >> 3;                  // 0..127
    const int cls  = l & 3;
    const int nt2  = (l >> 2) & 15;
    const int b    = 2*x8 + (l >> 6);
    const int a0 = (nt2 >> 1) * 8, c0 = (nt2 & 1) * 32;
    const int r = cls >> 1, s = cls & 1;

    __shared__ __align__(16) short als[2][2*ACH];   // A: 2 halves x 8KB
    __shared__ __align__(16) short xsb[2][2*2560];  // B: 2 halves x [9][33][8]

    // ---- staging plan: t = wv + i*4, i<7 -> t in 0..27, active t<26 ----
    // t<16: A (half=t>>3, 8 x 1KB each); t=16..25: B (half=(t-16)>=5, 5 x 1KB)
    const short* gb[7]; size_t gstep[7]; int loff[7], isB[7], act[7];
    {
        const size_t awb = (((size_t)b*4 + cls)*32) * ACH;
        #pragma unroll
        for (int i = 0; i < 7; ++i) {
            int t = wv + i*4;
            act[i] = (t < 26);
            if (t < 16) {
                int half = t >> 3, u = t & 7;
                gb[i]    = aws + awb + half*ACH + u*512 + lane*8;
                gstep[i] = 2*ACH;  loff[i] = half*4096 + u*512;  isB[i] = 0;
            } else {
                int j = t - 16; if (j > 9) j = 9;
                int half = (j >= 5) ? 1 : 0, jj = j - half*5;
                int p = jj*64 + lane; if (p > 296) p = 296;
                int row = p / 33, col = p - row*33;
                gb[i] = xt + (((size_t)(b*32 + half)*66 + (a0 + r + row))*66
                              + (c0 + s + col)) * 8;
                gstep[i] = 2*66*66*8;  loff[i] = half*2560 + jj*512;  isB[i] = 1;
            }
        }
    }

    f32x4 acc[4][8];
    #pragma unroll
    for (int mi = 0; mi < 4; ++mi)
        #pragma unroll
        for (int ni = 0; ni < 8; ++ni)
            acc[mi][ni] = (f32x4){0.f, 0.f, 0.f, 0.f};

    const int nlo = lane & 15;
    const int q   = lane >> 4;
    const int dh  = q >> 1, dw = q & 1;

    // swizzled A-read byte offsets (per-thread constants)
    int aoff[4];
    #pragma unroll
    for (int mi = 0; mi < 4; ++mi) {
        int row  = wm*64 + mi*16 + nlo;
        aoff[mi] = ((row*64 + q*16) ^ ((nlo & 7) << 4)) >> 1;   // shorts
    }

    // prologue: stage double-chunk 0 into buffer 0
    #pragma unroll
    for (int i = 0; i < 7; ++i)
        if (act[i])
            async_ld16(gb[i], isB[i] ? &xsb[0][loff[i]] : &als[0][loff[i]]);

    for (int c = 0; c < 16; ++c) {
        __syncthreads();                 // drains: buf[c&1] ready
        const int sel = c & 1;
        if (c < 15) {                    // prefetch next double-chunk
            const int ps = sel ^ 1;
            #pragma unroll
            for (int i = 0; i < 7; ++i)
                if (act[i])
                    async_ld16(gb[i] + (size_t)(c+1)*gstep[i],
                               isB[i] ? &xsb[ps][loff[i]] : &als[ps][loff[i]]);
        }
        #pragma unroll
        for (int h = 0; h < 2; ++h) {
            const short* ab = &als[sel][h*4096];
            const short* xb = &xsb[sel][h*2560];
            bf16x8 af[4], bfr[8];
            #pragma unroll
            for (int mi = 0; mi < 4; ++mi)
                af[mi] = *(const bf16x8*)(ab + aoff[mi]);
            #pragma unroll
            for (int ni = 0; ni < 8; ++ni) {
                int a_local = wn*4 + (ni & 3);
                int colx    = nlo + (ni >> 2)*16 + dw;
                bfr[ni] = *(const bf16x8*)(xb + ((a_local + dh)*33 + colx)*8);
            }
            #pragma unroll
            for (int mi = 0; mi < 4; ++mi)
                #pragma unroll
                for (int ni = 0; ni < 8; ++ni)
                    acc[mi][ni] = __builtin_amdgcn_mfma_f32_16x16x32_bf16(
                        af[mi], bfr[ni], acc[mi][ni], 0, 0, 0);
        }
    }

    // ---- epilogue: bias + PReLU ----
    const float pa = prelu_a[0];
    #pragma unroll
    for (int mi = 0; mi < 4; ++mi) {
        #pragma unroll
        for (int reg = 0; reg < 4; ++reg) {
            int co = wm*64 + mi*16 + q*4 + reg;
            float bv = bias[co];
            #pragma unroll
            for (int ni = 0; ni < 8; ++ni) {
                int a_local = wn*4 + (ni & 3);
                int cg      = ni >> 2;
                int oh = 2*(a0 + a_local) + r;
                int ow = 2*(c0 + cg*16 + nlo) + s;
                float v = acc[mi][ni][reg] + bv;
                v = (v >= 0.f) ? v : pa*v;
                out[(((size_t)b*COUT_ + co)*OH_ + oh)*OW_ + ow] = v;
            }
        }
    }
}

// ---------------------------------------------------------------------------
// Middle fallback: gather-based MFMA deconv (needs only aws in ws).
// A read direct from global at the swizzled offset (16B aligned).
// ---------------------------------------------------------------------------
__global__ __launch_bounds__(256, 2) void deconv_mfma_gather(
    const float* __restrict__ x,
    const short* __restrict__ aws,
    const float* __restrict__ bias,
    const float* __restrict__ prelu_a,
    float* __restrict__ out)
{
    const int tid  = threadIdx.x;
    const int lane = tid & 63;
    const int wv   = tid >> 6;
    const int wm   = wv & 1, wn = wv >> 1;
    const int nt   = blockIdx.x;
    const int cls  = blockIdx.y;
    const int b    = blockIdx.z;
    const int a0 = (nt >> 2) * 8, c0 = (nt & 3) * 16;
    const int r = cls >> 1, s = cls & 1;

    __shared__ __align__(16) short xs[1280];

    int goff[5], gstep[5], gok[5];
    #pragma unroll
    for (int i = 0; i < 5; ++i) {
        int e    = tid + i*256;
        int ci_l = e & 7;
        int rc   = e >> 3;
        int row  = rc / 17;
        int col  = rc - row*17;
        int ih   = a0 - 1 + r + row;
        int iw   = c0 - 1 + s + col;
        int ok   = (rc < 153) && ((unsigned)ih < (unsigned)H_)
                              && ((unsigned)iw < (unsigned)W_);
        goff[i]  = ok ? (((b*CIN_ + ci_l)*H_ + ih)*W_ + iw) : 0;
        gstep[i] = ok ? (8*H_*W_) : 0;
        gok[i]   = ok;
    }
    const int nlo = lane & 15;
    const int q   = lane >> 4;
    const int dh  = q >> 1, dw = q & 1;

    const size_t awb = (((size_t)b*4 + cls)*32) * ACH;
    int aoff[4];
    #pragma unroll
    for (int mi = 0; mi < 4; ++mi) {
        int row  = wm*64 + mi*16 + nlo;
        aoff[mi] = ((row*64 + q*16) ^ ((nlo & 7) << 4)) >> 1;
    }

    f32x4 acc[4][4];
    #pragma unroll
    for (int mi = 0; mi < 4; ++mi)
        #pragma unroll
        for (int ni = 0; ni < 4; ++ni)
            acc[mi][ni] = (f32x4){0.f, 0.f, 0.f, 0.f};

    for (int chunk = 0; chunk < 32; ++chunk) {
        __syncthreads();
        #pragma unroll
        for (int i = 0; i < 5; ++i) {
            float v = x[goff[i] + chunk*gstep[i]];
            v = gok[i] ? v : 0.0f;
            xs[tid + i*256] = f2bf(v);
        }
        bf16x8 af[4];
        #pragma unroll
        for (int mi = 0; mi < 4; ++mi)
            af[mi] = *(const bf16x8*)(aws + awb + (size_t)chunk*ACH + aoff[mi]);
        __syncthreads();
        bf16x8 bfr[4];
        #pragma unroll
        for (int ni = 0; ni < 4; ++ni) {
            int a_local = wn*4 + ni;
            bfr[ni] = *(const bf16x8*)(xs + ((a_local + dh)*17 + (nlo + dw))*8);
        }
        #pragma unroll
        for (int mi = 0; mi < 4; ++mi)
            #pragma unroll
            for (int ni = 0; ni < 4; ++ni)
                acc[mi][ni] = __builtin_amdgcn_mfma_f32_16x16x32_bf16(
                    af[mi], bfr[ni], acc[mi][ni], 0, 0, 0);
    }

    const float pa = prelu_a[0];
    #pragma unroll
    for (int mi = 0; mi < 4; ++mi) {
        #pragma unroll
        for (int reg = 0; reg < 4; ++reg) {
            int co = wm*64 + mi*16 + q*4 + reg;
            float bv = bias[co];
            #pragma unroll
            for (int ni = 0; ni < 4; ++ni) {
                int a_local = wn*4 + ni;
                int oh = 2*(a0 + a_local) + r;
                int ow = 2*(c0 + nlo) + s;
                float v = acc[mi][ni][reg] + bv;
                v = (v >= 0.f) ? v : pa*v;
                out[(((size_t)b*COUT_ + co)*OH_ + oh)*OW_ + ow] = v;
            }
        }
    }
}

// ---------------------------------------------------------------------------
// Last-resort fallback: fp32 direct kernel, in-kernel weight synthesis, no ws.
// ---------------------------------------------------------------------------
__global__ __launch_bounds__(256) void deconv_fallback(
    const float* __restrict__ x,
    const float* __restrict__ weight,
    const float* __restrict__ tb, const float* __restrict__ tq,
    const float* __restrict__ tn, const float* __restrict__ tx,
    const float* __restrict__ mb, const float* __restrict__ mq,
    const float* __restrict__ mn, const float* __restrict__ mx,
    const float* __restrict__ feat,
    const float* __restrict__ bias, const float* __restrict__ prelu_a,
    float* __restrict__ out)
{
    const int tid    = threadIdx.x;
    const int tile   = blockIdx.x;
    const int coT    = blockIdx.y;
    const int b      = blockIdx.z;
    const int tile_h = tile >> 3, tile_w = tile & 7;
    const int a0 = tile_h * 8;
    const int c0 = tile_w * 8;
    const int co0 = coT * 64;

    const int tco = tid & 15;
    const int tpx = tid >> 4;
    const int rr  = tpx >> 2, rc = tpx & 3;

    __shared__ float xsf[4][100];
    __shared__ float wsh[4][16][64];

    float acc[4][4][4];
    #pragma unroll
    for (int i = 0; i < 4; ++i)
        #pragma unroll
        for (int j = 0; j < 4; ++j)
            #pragma unroll
            for (int c = 0; c < 4; ++c) acc[i][j][c] = 0.f;

    float f0 = feat[b*4 + 0], f1 = feat[b*4 + 1];
    float f2 = feat[b*4 + 2], f3 = feat[b*4 + 3];

    for (int chunk = 0; chunk < CIN_ / 4; ++chunk) {
        const int ci0 = chunk * 4;
        __syncthreads();
        for (int e = tid; e < 400; e += 256) {
            int ci_l = e / 100; int rem = e - ci_l * 100;
            int rI = rem / 10;  int cI = rem - rI * 10;
            int ih = a0 - 1 + rI, iw = c0 - 1 + cI;
            float v = 0.f;
            if ((unsigned)ih < (unsigned)H_ && (unsigned)iw < (unsigned)W_)
                v = x[(((size_t)b * CIN_ + ci0 + ci_l) * H_ + ih) * W_ + iw];
            xsf[ci_l][rem] = v;
        }
        #pragma unroll
        for (int k = 0; k < 4; ++k) {
            int g = tid + k * 256;
            int ci_l = g >> 8; int rrem = g & 255;
            int co_l = rrem >> 2; int tg = (rrem & 3) * 4;
            int cico = (ci0 + ci_l) * COUT_ + co0 + co_l;
            int e = cico * 16 + tg;
            float4 w  = *(const float4*)(weight + e);
            float4 vb = *(const float4*)(tb + e);
            float4 vq = *(const float4*)(tq + e);
            float4 vn = *(const float4*)(tn + e);
            float4 vx = *(const float4*)(tx + e);
            float sb = mb[cico] * f0, sq = mq[cico] * f1;
            float sn = mn[cico] * f2, sx = mx[cico] * f3;
            float4 wvv;
            wvv.x = w.x + sb*vb.x + sq*vq.x + sn*vn.x + sx*vx.x;
            wvv.y = w.y + sb*vb.y + sq*vq.y + sn*vn.y + sx*vx.y;
            wvv.z = w.z + sb*vb.z + sq*vq.z + sn*vn.z + sx*vx.z;
            wvv.w = w.w + sb*vb.w + sq*vq.w + sn*vn.w + sx*vx.w;
            wsh[ci_l][tg + 0][co_l] = wvv.x;
            wsh[ci_l][tg + 1][co_l] = wvv.y;
            wsh[ci_l][tg + 2][co_l] = wvv.z;
            wsh[ci_l][tg + 3][co_l] = wvv.w;
        }
        __syncthreads();
        #pragma unroll
        for (int ci_l = 0; ci_l < 4; ++ci_l) {
            float xpv[4][4];
            #pragma unroll
            for (int i = 0; i < 4; ++i)
                #pragma unroll
                for (int j = 0; j < 4; ++j)
                    xpv[i][j] = xsf[ci_l][(rr*2 + i) * 10 + rc*2 + j];
            #pragma unroll
            for (int kh = 0; kh < 4; ++kh) {
                const int rpar = (kh & 1) ? 0 : 1;
                const int offh = (kh == 0) ? 2 : (kh == 3) ? 0 : 1;
                #pragma unroll
                for (int kw = 0; kw < 4; ++kw) {
                    const int spar = (kw & 1) ? 0 : 1;
                    const int offw = (kw == 0) ? 2 : (kw == 3) ? 0 : 1;
                    float4 wvv = *(const float4*)&wsh[ci_l][kh*4 + kw][tco*4];
                    float wr[4] = {wvv.x, wvv.y, wvv.z, wvv.w};
                    #pragma unroll
                    for (int da = 0; da < 2; ++da)
                        #pragma unroll
                        for (int dc = 0; dc < 2; ++dc) {
                            const float xvv = xpv[da + offh][dc + offw];
                            #pragma unroll
                            for (int cc = 0; cc < 4; ++cc)
                                acc[2*da + rpar][2*dc + spar][cc] =
                                    fmaf(wr[cc], xvv, acc[2*da + rpar][2*dc + spar][cc]);
                        }
                }
            }
        }
    }
    const float pa  = prelu_a[0];
    const int oh0 = tile_h * 16 + rr * 4;
    const int ow0 = tile_w * 16 + rc * 4;
    #pragma unroll
    for (int cc = 0; cc < 4; ++cc) {
        const int co = co0 + tco * 4 + cc;
        const float bv = bias[co];
        #pragma unroll
        for (int dr = 0; dr < 4; ++dr)
            #pragma unroll
            for (int dw2 = 0; dw2 < 4; ++dw2) {
                float v = acc[dr][dw2][cc] + bv;
                v = (v >= 0.f) ? v : pa * v;
                out[(((size_t)b * COUT_ + co) * OH_ + (oh0 + dr)) * OW_ + (ow0 + dw2)] = v;
            }
    }
}

extern "C" void kernel_launch(void* const* d_in, const int* in_sizes, int n_in,
                              void* d_out, int out_size, void* d_ws, size_t ws_size,
                              hipStream_t stream) {
    (void)in_sizes; (void)n_in; (void)out_size;
    const float* x      = (const float*)d_in[0];
    const float* feat   = (const float*)d_in[1];
    const float* weight = (const float*)d_in[2];
    const float* tb     = (const float*)d_in[3];
    const float* tq     = (const float*)d_in[4];
    const float* tn     = (const float*)d_in[5];
    const float* tx     = (const float*)d_in[6];
    const float* mb     = (const float*)d_in[7];
    const float* mq     = (const float*)d_in[8];
    const float* mn     = (const float*)d_in[9];
    const float* mx     = (const float*)d_in[10];
    const float* bias   = (const float*)d_in[11];
    const float* prelu  = (const float*)d_in[12];
    float* out = (float*)d_out;

    const size_t aws_sz = (size_t)B_ * 4 * 32 * ACH * sizeof(short);        // 16.78 MB
    const size_t xt_sz  = (size_t)B_ * 32 * 66 * 66 * 8 * sizeof(short);    // 35.68 MB

    if (ws_size >= aws_sz + xt_sz) {
        short* aws = (short*)d_ws;
        short* xt  = (short*)((char*)d_ws + aws_sz);
        prep_fused<<<dim3(1056 + 512), 256, 0, stream>>>(
            x, weight, tb, tq, tn, tx, mb, mq, mn, mx, feat, aws, xt);
        deconv_mfma6<<<dim3(1024), 256, 0, stream>>>(
            aws, xt, bias, prelu, out);
    } else if (ws_size >= aws_sz) {
        short* aws = (short*)d_ws;
        synth_aws<<<dim3(32, 16), 256, 0, stream>>>(
            weight, tb, tq, tn, tx, mb, mq, mn, mx, feat, aws);
        deconv_mfma_gather<<<dim3(32, 4, 16), 256, 0, stream>>>(
            x, aws, bias, prelu, out);
    } else {
        deconv_fallback<<<dim3(64, 2, 16), 256, 0, stream>>>(
            x, weight, tb, tq, tn, tx, mb, mq, mn, mx, feat, bias, prelu, out);
    }
}